// Round 1
// baseline (675.779 us; speedup 1.0000x reference)
//
#include <hip/hip_runtime.h>

// SparseConv3d(32->64, k=3, s=2, p=1), (21,800,704) grid, nnz=220939.
// Round 5: site-bucketed LDS accumulation.
// Theory: previous kernel was bound by 47.7M global f32 atomics (745K pairs
// x 64 couts) + a 396MB dense zero pass. This version buckets pairs by
// 128-site output range, accumulates each bucket in a 32KB LDS tile
// (ds_add_f32), and writes every output line exactly once with plain
// coalesced stores (which also covers the zeroing). Global atomics only on
// the (statistically never) bucket-overflow fallback path.
//
// Pipeline:
//   prep    : W[27][32][64] -> WT[27][64][32]; zero bucket counters
//   build   : parity rulebook -> packed pairs (point<<12|k<<7|loc) bucketed
//             by site>>7, via per-bucket atomic counters
//   scatter : block = one 128-site tile. counting-sort pairs by k (LDS),
//             per k-run load lane's weight column (8xb128), per pair
//             broadcast feat row + 16 v_pk_fma, ds_add_f32 into tile,
//             then one coalesced 32KB store.
//   fixup   : old-style global-atomic scatter for overflowed pairs (runs
//             after scatter's stores -> no ordering hazard).

#define CIN    32
#define COUT   64
#define OXD    11
#define OYD    400
#define OZD    352
#define NOUT   (OXD * OYD * OZD)      // 1,548,800
#define BSITES 128
#define NBUCK  (NOUT / BSITES)        // 12,100 (exact)
#define CAP    256                    // pairs per bucket (== block size)
#define OVCAP  32768
#define NWT    (27 * COUT * CIN)      // 55,296 floats

typedef float v2f __attribute__((ext_vector_type(2)));

// ---------------------------------------------------------------- prep ----
__global__ __launch_bounds__(256) void prep(const float* __restrict__ w,
                                            float* __restrict__ wt,
                                            int* __restrict__ gcnt,
                                            int* __restrict__ ovcnt) {
    const int i = blockIdx.x * 256 + threadIdx.x;
    if (i < NWT) {
        const int k  = i >> 11;          // 2048 = 64*32 per offset
        const int rm = i & 2047;
        const int co = rm >> 5;
        const int ci = rm & 31;
        wt[i] = w[k * (CIN * COUT) + ci * COUT + co];   // WT[k][co][ci]
    }
    if (i < NBUCK) gcnt[i] = 0;
    if (i == NBUCK) *ovcnt = 0;
}

// --------------------------------------------------------------- build ----
__global__ __launch_bounds__(256) void build_pairs(
    const int* __restrict__ coords,
    int* __restrict__ arena,
    int* __restrict__ gcnt,
    int* __restrict__ ovcnt,
    int2* __restrict__ ovlist,
    int nnz)
{
    const int n = blockIdx.x * 256 + threadIdx.x;
    if (n >= nnz) return;

    const int cx = coords[3 * n + 0];
    const int cy = coords[3 * n + 1];
    const int cz = coords[3 * n + 2];

    int kxl[2], oxl[2], nx;
    int kyl[2], oyl[2], ny;
    int kzl[2], ozl[2], nz;
    {
        const int c1 = cx + 1;
        if (c1 & 1) { kxl[0] = 1; oxl[0] = c1 >> 1; nx = 1; }
        else { kxl[0] = 2; oxl[0] = (c1 - 2) >> 1; nx = 1;
               if ((c1 >> 1) < OXD) { kxl[1] = 0; oxl[1] = c1 >> 1; nx = 2; } }
    }
    {
        const int c1 = cy + 1;
        if (c1 & 1) { kyl[0] = 1; oyl[0] = c1 >> 1; ny = 1; }
        else { kyl[0] = 2; oyl[0] = (c1 - 2) >> 1; ny = 1;
               if ((c1 >> 1) < OYD) { kyl[1] = 0; oyl[1] = c1 >> 1; ny = 2; } }
    }
    {
        const int c1 = cz + 1;
        if (c1 & 1) { kzl[0] = 1; ozl[0] = c1 >> 1; nz = 1; }
        else { kzl[0] = 2; ozl[0] = (c1 - 2) >> 1; nz = 1;
               if ((c1 >> 1) < OZD) { kzl[1] = 0; ozl[1] = c1 >> 1; nz = 2; } }
    }

    for (int ix = 0; ix < nx; ++ix)
        for (int iy = 0; iy < ny; ++iy)
            for (int iz = 0; iz < nz; ++iz) {
                const int k    = kxl[ix] * 9 + kyl[iy] * 3 + kzl[iz];
                const int site = (oxl[ix] * OYD + oyl[iy]) * OZD + ozl[iz];
                const int bkt  = site >> 7;          // /BSITES
                const int loc  = site & (BSITES - 1);
                const int slot = atomicAdd(&gcnt[bkt], 1);
                if (slot < CAP) {
                    arena[(size_t)bkt * CAP + slot] = (n << 12) | (k << 7) | loc;
                } else {
                    const int o = atomicAdd(ovcnt, 1);
                    if (o < OVCAP) ovlist[o] = make_int2(site, (n << 5) | k);
                }
            }
}

// ------------------------------------------------------------- scatter ----
__global__ __launch_bounds__(256, 4) void spconv_scatter(
    const float* __restrict__ feat,
    const float* __restrict__ wt,
    const int*   __restrict__ arena,
    const int*   __restrict__ gcnt,
    float*       __restrict__ out)
{
    __shared__ float tile[BSITES][COUT];   // 32 KB, == output layout
    __shared__ int   sorted[CAP];
    __shared__ int   khist[27];
    __shared__ int   kbase[27];

    const int t    = threadIdx.x;
    const int lane = t & 63;
    const int wid  = t >> 6;
    const int b    = blockIdx.x;
    const int cnt  = min(gcnt[b], CAP);

    if (t < 27) khist[t] = 0;
    __syncthreads();

    // one pair per thread (CAP == blockDim): load + histogram by k
    int myp = 0, myk = 0;
    if (t < cnt) {
        myp = arena[(size_t)b * CAP + t];
        myk = (myp >> 7) & 31;
        atomicAdd(&khist[myk], 1);
    }
    // zero the accumulation tile in the same phase
    float4* t4 = (float4*)&tile[0][0];
    #pragma unroll
    for (int r = 0; r < 8; ++r) t4[t + r * 256] = make_float4(0.f, 0.f, 0.f, 0.f);
    __syncthreads();

    // exclusive scan of 27 bins, wave-parallel in wave 0
    if (wid == 0) {
        const int h = (lane < 27) ? khist[lane] : 0;
        int v = h;
        #pragma unroll
        for (int off = 1; off < 32; off <<= 1) {
            const int u = __shfl_up(v, off);
            if (lane >= off) v += u;
        }
        if (lane < 27) kbase[lane] = v - h;
    }
    __syncthreads();
    if (t < cnt) {
        const int pos = atomicAdd(&kbase[myk], 1);
        sorted[pos] = myp;
    }
    __syncthreads();

    // accumulate: waves take contiguous chunks of the k-sorted list so the
    // per-lane weight column (8xb128 -> 32 VGPR) reloads only per k-run.
    const int c  = (cnt + 3) >> 2;
    const int jb = min(wid * c, cnt);
    const int je = min(jb + c, cnt);
    float4 wv[8];
    int curk = -1;
    for (int j = jb; j < je; ++j) {
        const int pk  = __builtin_amdgcn_readfirstlane(sorted[j]);
        const int k   = (pk >> 7) & 31;
        const int loc = pk & (BSITES - 1);
        const int pt  = pk >> 12;
        if (k != curk) {
            curk = k;
            const float4* __restrict__ wp =
                (const float4*)(wt + ((size_t)k * COUT + lane) * CIN);
            #pragma unroll
            for (int bb = 0; bb < 8; ++bb) wv[bb] = wp[bb];
        }
        const float4* __restrict__ fp = (const float4*)(feat + (size_t)pt * CIN);
        v2f a0 = {0.f, 0.f}, a1 = {0.f, 0.f};
        #pragma unroll
        for (int bb = 0; bb < 8; ++bb) {
            const float4 f = fp[bb];          // wave-uniform -> broadcast
            const float4 wb = wv[bb];
            v2f f01 = {f.x, f.y}, f23 = {f.z, f.w};
            v2f w01 = {wb.x, wb.y}, w23 = {wb.z, wb.w};
#if __has_builtin(__builtin_elementwise_fma)
            a0 = __builtin_elementwise_fma(f01, w01, a0);
            a1 = __builtin_elementwise_fma(f23, w23, a1);
#else
            a0[0] = fmaf(f01[0], w01[0], a0[0]);
            a0[1] = fmaf(f01[1], w01[1], a0[1]);
            a1[0] = fmaf(f23[0], w23[0], a1[0]);
            a1[1] = fmaf(f23[1], w23[1], a1[1]);
#endif
        }
        atomicAdd(&tile[loc][lane], (a0[0] + a0[1]) + (a1[0] + a1[1]));  // ds_add_f32
    }
    __syncthreads();

    // single coalesced write of the whole tile — covers zeroing too
    float4* __restrict__ o4 = (float4*)(out + (size_t)b * (BSITES * COUT));
    #pragma unroll
    for (int r = 0; r < 8; ++r) o4[t + r * 256] = t4[t + r * 256];
}

// --------------------------------------------------------------- fixup ----
__global__ __launch_bounds__(256) void fixup_overflow(
    const float* __restrict__ feat,
    const float* __restrict__ wt,
    const int2*  __restrict__ ovlist,
    const int*   __restrict__ ovcnt,
    float*       __restrict__ out)
{
    const int lane = threadIdx.x & 63;
    const int gw   = blockIdx.x * 4 + (threadIdx.x >> 6);
    const int n    = min(*ovcnt, OVCAP);
    for (int e = gw; e < n; e += 128 * 4) {
        const int2 r   = ovlist[e];
        const int site = r.x;
        const int pt   = r.y >> 5;
        const int k    = r.y & 31;
        const float4* __restrict__ wp =
            (const float4*)(wt + ((size_t)k * COUT + lane) * CIN);
        const float4* __restrict__ fp = (const float4*)(feat + (size_t)pt * CIN);
        float acc = 0.f;
        #pragma unroll
        for (int bb = 0; bb < 8; ++bb) {
            const float4 f = fp[bb];
            const float4 w = wp[bb];
            acc = fmaf(f.x, w.x, acc);
            acc = fmaf(f.y, w.y, acc);
            acc = fmaf(f.z, w.z, acc);
            acc = fmaf(f.w, w.w, acc);
        }
        atomicAdd(out + (size_t)site * COUT + lane, acc);
    }
}

// -------------------------------------------------------------- launch ----
extern "C" void kernel_launch(void* const* d_in, const int* in_sizes, int n_in,
                              void* d_out, int out_size, void* d_ws, size_t ws_size,
                              hipStream_t stream) {
    const float* feat   = (const float*)d_in[0];
    const int*   coords = (const int*)d_in[1];
    const float* weight = (const float*)d_in[2];
    float*       out    = (float*)d_out;
    const int nnz = in_sizes[0] / CIN;            // 220939

    // workspace layout (~12.9 MB, well under previous 47.7 MB usage)
    float* WT     = (float*)d_ws;                 // NWT floats
    int*   gcnt   = (int*)(WT + NWT);             // NBUCK
    int*   ovcnt  = gcnt + NBUCK;                 // 1 (+1 pad)
    int2*  ovlist = (int2*)(ovcnt + 2);           // OVCAP
    int*   arena  = (int*)(ovlist + OVCAP);       // NBUCK*CAP

    prep<<<(NWT + 255) / 256, 256, 0, stream>>>(weight, WT, gcnt, ovcnt);
    build_pairs<<<(nnz + 255) / 256, 256, 0, stream>>>(coords, arena, gcnt,
                                                       ovcnt, ovlist, nnz);
    spconv_scatter<<<NBUCK, 256, 0, stream>>>(feat, WT, arena, gcnt, out);
    fixup_overflow<<<128, 256, 0, stream>>>(feat, WT, ovlist, ovcnt, out);
}